// Round 1
// baseline (287.035 us; speedup 1.0000x reference)
//
#include <hip/hip_runtime.h>

#define EPS 1e-6f
#define NB 16
#define LL 4096
#define HE 512

typedef __attribute__((ext_vector_type(8))) short short8;
typedef __attribute__((ext_vector_type(4))) float f32x4;

__device__ __forceinline__ unsigned short f2bf(float f) {
    union { float f; unsigned u; } v; v.f = f;
    unsigned r = v.u + 0x7FFFu + ((v.u >> 16) & 1u);  // RNE
    return (unsigned short)(r >> 16);
}

// ---------------- stats: sumV / sumsq per (b, n) -------------------------
__global__ __launch_bounds__(256) void k_stats(const float* __restrict__ q,
                                               float* __restrict__ sumV,
                                               float* __restrict__ sumsq) {
    int b = blockIdx.x >> 6;
    int lc = blockIdx.x & 63;
    int t = threadIdx.x;
    int n4 = (t & 127) << 2;
    const float* base = q + (size_t)b * LL * HE;
    float s0=0,s1=0,s2=0,s3=0, q0=0,q1=0,q2=0,q3=0;
    int r0 = lc * 64 + (t >> 7);
    #pragma unroll 4
    for (int r = r0; r < lc * 64 + 64; r += 2) {
        float4 v = *(const float4*)(base + (size_t)r * HE + n4);
        s0 += v.x; s1 += v.y; s2 += v.z; s3 += v.w;
        q0 += v.x*v.x; q1 += v.y*v.y; q2 += v.z*v.z; q3 += v.w*v.w;
    }
    int idx = b * HE + n4;
    atomicAdd(&sumV[idx+0], s0); atomicAdd(&sumsq[idx+0], q0);
    atomicAdd(&sumV[idx+1], s1); atomicAdd(&sumsq[idx+1], q1);
    atomicAdd(&sumV[idx+2], s2); atomicAdd(&sumsq[idx+2], q2);
    atomicAdd(&sumV[idx+3], s3); atomicAdd(&sumsq[idx+3], q3);
}

// ---------------- finalize: c[b,n], inv_norm[b,n] ------------------------
__global__ __launch_bounds__(256) void k_finalize(const float* __restrict__ sumV,
                                                  const float* __restrict__ sumsq,
                                                  float* __restrict__ cvec,
                                                  float* __restrict__ invn) {
    int i = blockIdx.x * 256 + threadIdx.x;  // 0..8191
    float sv = sumV[i];
    float inv = 1.0f / sqrtf(sumsq[i]);
    invn[i] = inv;
    cvec[i] = (sv * inv + EPS) * inv;        // q_colsum / norm
}

// ---------------- transpose: Vt[b, n, l] bf16 ----------------------------
__global__ __launch_bounds__(256) void k_transpose(const float* __restrict__ q,
                                                   unsigned short* __restrict__ Vt) {
    __shared__ __attribute__((aligned(16))) unsigned short lds[64][68];
    int blk = blockIdx.x;
    int nt = blk & 7, lt = (blk >> 3) & 63, b = blk >> 9;
    int t = threadIdx.x;
    int row = t >> 4;            // 0..15  (l-local in phase 1, n-local in phase 2)
    int col = (t & 15) << 2;     // 0..60
    const float* base = q + ((size_t)b * LL + lt * 64) * HE + nt * 64;
    #pragma unroll
    for (int i = 0; i < 4; i++) {
        float4 v = *(const float4*)(base + (size_t)(row + i * 16) * HE + col);
        lds[col+0][row + i*16] = f2bf(v.x);
        lds[col+1][row + i*16] = f2bf(v.y);
        lds[col+2][row + i*16] = f2bf(v.z);
        lds[col+3][row + i*16] = f2bf(v.w);
    }
    __syncthreads();
    unsigned short* ob = Vt + ((size_t)b * HE + nt * 64) * LL + lt * 64;
    #pragma unroll
    for (int i = 0; i < 4; i++) {
        int n = row + i * 16;
        ushort4 w;
        w.x = lds[n][col+0]; w.y = lds[n][col+1];
        w.z = lds[n][col+2]; w.w = lds[n][col+3];
        *(ushort4*)(ob + (size_t)n * LL + col) = w;
    }
}

// ---------------- Gram GEMM: KQb[b,n,m] = G * invn * invm (bf16) ---------
__global__ __launch_bounds__(256) void k_gram(const unsigned short* __restrict__ Vt,
                                              const float* __restrict__ invn,
                                              unsigned short* __restrict__ KQb) {
    __shared__ __attribute__((aligned(16))) unsigned short la[128][72];
    __shared__ __attribute__((aligned(16))) unsigned short lb[128][72];
    int blk = blockIdx.x;
    int b = blk >> 4;
    int nt = (blk >> 2) & 3, mt = blk & 3;
    int N0 = nt * 128, M0 = mt * 128;
    int t = threadIdx.x;
    int w = t >> 6, lane = t & 63;
    int wr = w >> 1, wc = w & 1;
    f32x4 acc[4][4] = {};
    const unsigned short* pa = Vt + (size_t)(b * HE + N0) * LL;
    const unsigned short* pb = Vt + (size_t)(b * HE + M0) * LL;
    int srow = t >> 3;            // 0..31
    int su = (t & 7) * 8;         // 0..56
    for (int kb = 0; kb < LL / 64; kb++) {
        int k0 = kb * 64;
        #pragma unroll
        for (int p = 0; p < 4; p++) {
            int r = p * 32 + srow;
            *(uint4*)&la[r][su] = *(const uint4*)(pa + (size_t)r * LL + k0 + su);
            *(uint4*)&lb[r][su] = *(const uint4*)(pb + (size_t)r * LL + k0 + su);
        }
        __syncthreads();
        #pragma unroll
        for (int ks = 0; ks < 2; ks++) {
            short8 af[4], bfr[4];
            int ko = ks * 32 + (lane >> 4) * 8;
            #pragma unroll
            for (int i = 0; i < 4; i++)
                af[i] = *(const short8*)&la[wr*64 + i*16 + (lane & 15)][ko];
            #pragma unroll
            for (int j = 0; j < 4; j++)
                bfr[j] = *(const short8*)&lb[wc*64 + j*16 + (lane & 15)][ko];
            #pragma unroll
            for (int i = 0; i < 4; i++)
                #pragma unroll
                for (int j = 0; j < 4; j++)
                    acc[i][j] = __builtin_amdgcn_mfma_f32_16x16x32_bf16(af[i], bfr[j], acc[i][j], 0, 0, 0);
        }
        __syncthreads();
    }
    // epilogue: scale by inv_norm outer product, store bf16
    #pragma unroll
    for (int i = 0; i < 4; i++) {
        int nbase = N0 + wr*64 + i*16 + (lane >> 4) * 4;
        #pragma unroll
        for (int j = 0; j < 4; j++) {
            int m = M0 + wc*64 + j*16 + (lane & 15);
            float im = invn[b * HE + m];
            #pragma unroll
            for (int jj = 0; jj < 4; jj++) {
                int n = nbase + jj;
                float v = acc[i][j][jj] * invn[b * HE + n] * im;
                KQb[((size_t)(b * HE + n)) * HE + m] = f2bf(v);
            }
        }
    }
}

// ---------------- part GEMM (P^T) + fused tailor + epilogue --------------
__global__ __launch_bounds__(256) void k_part(const float* __restrict__ q,
                                              const unsigned short* __restrict__ KQb,
                                              const float* __restrict__ cvec,
                                              const float* __restrict__ sumV,
                                              const float* __restrict__ gamma,
                                              float* __restrict__ out) {
    __shared__ __attribute__((aligned(16))) unsigned short la[128][72];
    __shared__ __attribute__((aligned(16))) unsigned short lb[128][72];
    __shared__ float lds_c[512];
    __shared__ float lds_d[128][2];
    int blk = blockIdx.x;
    int b = blk >> 7;
    int mt = (blk >> 5) & 3;
    int lt = blk & 31;
    int M0 = mt * 128, L0 = lt * 128;
    int t = threadIdx.x;
    int w = t >> 6, lane = t & 63;
    int wr = w >> 1, wc = w & 1;
    lds_c[t]       = cvec[b * HE + t];
    lds_c[t + 256] = cvec[b * HE + t + 256];
    __syncthreads();
    f32x4 acc[4][4] = {};
    int srow = t >> 3;
    int su = (t & 7) * 8;
    int brow = t >> 1;
    int bhalf = (t & 1) * 32;
    const float* qb = q + ((size_t)b * LL + L0 + brow) * HE;
    float dpart = 0.0f;
    for (int kb = 0; kb < HE / 64; kb++) {
        int k0 = kb * 64;
        #pragma unroll
        for (int p = 0; p < 4; p++) {
            int r = p * 32 + srow;
            *(uint4*)&la[r][su] = *(const uint4*)(KQb + ((size_t)(b*HE + M0 + r)) * HE + k0 + su);
        }
        const float* src = qb + k0 + bhalf;
        #pragma unroll
        for (int g = 0; g < 4; g++) {
            float4 v0 = *(const float4*)(src + g * 8);
            float4 v1 = *(const float4*)(src + g * 8 + 4);
            short8 s;
            s[0]=f2bf(v0.x); s[1]=f2bf(v0.y); s[2]=f2bf(v0.z); s[3]=f2bf(v0.w);
            s[4]=f2bf(v1.x); s[5]=f2bf(v1.y); s[6]=f2bf(v1.z); s[7]=f2bf(v1.w);
            *(short8*)&lb[brow][bhalf + g*8] = s;
            int ci = k0 + bhalf + g * 8;
            dpart += v0.x*lds_c[ci+0] + v0.y*lds_c[ci+1] + v0.z*lds_c[ci+2] + v0.w*lds_c[ci+3]
                   + v1.x*lds_c[ci+4] + v1.y*lds_c[ci+5] + v1.z*lds_c[ci+6] + v1.w*lds_c[ci+7];
        }
        __syncthreads();
        #pragma unroll
        for (int ks = 0; ks < 2; ks++) {
            short8 af[4], bfr[4];
            int ko = ks * 32 + (lane >> 4) * 8;
            #pragma unroll
            for (int i = 0; i < 4; i++)
                af[i] = *(const short8*)&la[wr*64 + i*16 + (lane & 15)][ko];
            #pragma unroll
            for (int j = 0; j < 4; j++)
                bfr[j] = *(const short8*)&lb[wc*64 + j*16 + (lane & 15)][ko];
            #pragma unroll
            for (int i = 0; i < 4; i++)
                #pragma unroll
                for (int j = 0; j < 4; j++)
                    acc[i][j] = __builtin_amdgcn_mfma_f32_16x16x32_bf16(af[i], bfr[j], acc[i][j], 0, 0, 0);
        }
        __syncthreads();
    }
    lds_d[brow][t & 1] = dpart;
    __syncthreads();
    float gma = gamma[0];
    #pragma unroll
    for (int j = 0; j < 4; j++) {
        int lloc = wc*64 + j*16 + (lane & 15);
        int l = L0 + lloc;
        float dtot = lds_d[lloc][0] + lds_d[lloc][1];
        float tailor = 1.0f / (512.0f + dtot);
        #pragma unroll
        for (int i = 0; i < 4; i++) {
            int m4 = M0 + wr*64 + i*16 + (lane >> 4) * 4;
            size_t off = ((size_t)b * LL + l) * HE + m4;
            float4 qv = *(const float4*)(q + off);
            float4 vs = *(const float4*)(sumV + b * HE + m4);
            float4 o;
            o.x = qv.x + gma * (vs.x + acc[i][j][0]) * tailor;
            o.y = qv.y + gma * (vs.y + acc[i][j][1]) * tailor;
            o.z = qv.z + gma * (vs.z + acc[i][j][2]) * tailor;
            o.w = qv.w + gma * (vs.w + acc[i][j][3]) * tailor;
            *(float4*)(out + off) = o;
        }
    }
}

extern "C" void kernel_launch(void* const* d_in, const int* in_sizes, int n_in,
                              void* d_out, int out_size, void* d_ws, size_t ws_size,
                              hipStream_t stream) {
    const float* q     = (const float*)d_in[0];
    const float* gamma = (const float*)d_in[4];
    float* out = (float*)d_out;
    char* ws = (char*)d_ws;
    // ws layout
    float* sumV  = (float*)(ws);                       // 32 KiB
    float* sumsq = (float*)(ws + 32768);               // 32 KiB
    float* cvec  = (float*)(ws + 65536);               // 32 KiB
    float* invn  = (float*)(ws + 98304);               // 32 KiB
    unsigned short* KQb = (unsigned short*)(ws + 131072);            // 8 MiB
    unsigned short* Vt  = (unsigned short*)(ws + 131072 + 8388608);  // 64 MiB

    hipMemsetAsync(d_ws, 0, 65536, stream);  // zero atomics targets (sumV, sumsq)
    k_stats   <<<NB * 64, 256, 0, stream>>>(q, sumV, sumsq);
    k_finalize<<<32, 256, 0, stream>>>(sumV, sumsq, cvec, invn);
    k_transpose<<<NB * 64 * 8, 256, 0, stream>>>(q, Vt);
    k_gram    <<<NB * 16, 256, 0, stream>>>(Vt, invn, KQb);
    k_part    <<<NB * 4 * 32, 256, 0, stream>>>(q, KQb, cvec, sumV, gamma, out);
}